// Round 7
// baseline (473.517 us; speedup 1.0000x reference)
//
#include <hip/hip_runtime.h>
#include <stdint.h>
#include <stddef.h>

typedef __bf16 bf16x8 __attribute__((ext_vector_type(8)));
typedef float  f32x4  __attribute__((ext_vector_type(4)));
typedef unsigned short u16;
typedef unsigned char  u8;

#define NIN   784
#define NINP  896
#define NH    1024
#define NE    512
#define ND    64
#define NOUTP 1024

#define SBAR()   __builtin_amdgcn_s_barrier()
#define SCHED0() __builtin_amdgcn_sched_barrier(0)
#define LGKM0()  asm volatile("s_waitcnt lgkmcnt(0)" ::: "memory")
#define VM4()    asm volatile("s_waitcnt vmcnt(4)" ::: "memory")
#define VM3()    asm volatile("s_waitcnt vmcnt(3)" ::: "memory")
#define VM0()    asm volatile("s_waitcnt vmcnt(0)" ::: "memory")
#define FSWZ(r)  (((r) ^ ((r) >> 2)) & 3)
#define GLDS(g, l) __builtin_amdgcn_global_load_lds((__attribute__((address_space(1))) void*)(g), (__attribute__((address_space(3))) void*)(l), 16, 0, 0)

static __device__ __forceinline__ u16 f2bf(float f) {
  union { float f; unsigned u; } v; v.f = f;
  unsigned r = v.u + 0x7fffu + ((v.u >> 16) & 1u);
  return (u16)(r >> 16);
}
static __device__ __forceinline__ float bf2f(u16 b) {
  union { unsigned u; float f; } v; v.u = ((unsigned)b) << 16; return v.f;
}
// f32 -> OCP e4m3fn, RNE, subnormal-correct
static __device__ __forceinline__ u8 f2fp8(float f) {
  union { float f; unsigned u; } v; v.f = f;
  u8 s = (u8)((v.u >> 24) & 0x80);
  float a = __builtin_fabsf(f);
  if (a >= 464.f) return s | 0x7E;                 // clamp to 448
  v.f = a;
  int e = (int)((v.u >> 23) & 0xFF) - 127;
  if (e < -6) { int r = (int)rintf(a * 512.f); return s | (u8)r; }
  unsigned m = v.u & 0x7FFFFF;
  unsigned keep = m >> 20, rest = m & 0xFFFFF;
  keep += (rest > 0x80000 || (rest == 0x80000 && (keep & 1))) ? 1u : 0u;
  if (keep == 8) { keep = 0; ++e; }
  if (e > 8) return s | 0x7E;
  return s | (u8)((e + 7) << 3) | (u8)keep;
}
static __device__ __forceinline__ unsigned pack4fp8(float a, float b, float c, float d) {
  return (unsigned)f2fp8(a) | ((unsigned)f2fp8(b) << 8) |
         ((unsigned)f2fp8(c) << 16) | ((unsigned)f2fp8(d) << 24);
}

// fp8 tiled layout: blk=(r>>8)*(Cp>>6)+(c>>6) [16384 B], off=(r&255)*64+((((c>>4)&3)^FSWZ(r))<<4)+(c&15)

// ---------- casts ----------
__global__ void cast_tiled8(const float* __restrict__ src, u8* __restrict__ dst,
                            int R, int C, int Cp) {
  int r = blockIdx.y;
  int c4 = (blockIdx.x * blockDim.x + threadIdx.x) * 4;
  if (c4 >= Cp) return;
  unsigned o = 0;
  if (r < R && c4 < C) {
    const float4 v = *(const float4*)&src[(size_t)r * C + c4];
    o = pack4fp8(v.x, v.y, v.z, v.w);
  }
  size_t off = ((size_t)(r >> 8) * (Cp >> 6) + (c4 >> 6)) * 16384
             + ((r & 255) << 6) + ((((c4 >> 4) & 3) ^ FSWZ(r)) << 4) + (c4 & 15);
  *(unsigned*)&dst[off] = o;
}

__global__ void cast_rm8(const float* __restrict__ src, u8* __restrict__ dst, int R, int C) {
  int r = blockIdx.y;
  int c4 = (blockIdx.x * blockDim.x + threadIdx.x) * 4;
  if (c4 >= C) return;
  const float4 v = *(const float4*)&src[(size_t)r * C + c4];
  *(unsigned*)&dst[(size_t)r * C + c4] = pack4fp8(v.x, v.y, v.z, v.w);
}

__global__ void cast_rm64swz(const float* __restrict__ src, u16* __restrict__ dst, int R) {
  int r = blockIdx.x, d = threadIdx.x;
  if (r >= R) return;
  dst[r * 64 + (((d >> 3) ^ (r & 7)) << 3) + (d & 7)] = f2bf(src[r * 64 + d]);
}

__global__ void emb_prep(const float* __restrict__ emb, u16* __restrict__ ebf,
                         float* __restrict__ cvec) {
  int j = blockIdx.x, l = threadIdx.x;
  float v = emb[j * ND + l];
  ebf[j * 64 + (((l >> 3) ^ (j & 7)) << 3) + (l & 7)] = f2bf(v);
  float s = v * v;
  #pragma unroll
  for (int off = 32; off > 0; off >>= 1) s += __shfl_down(s, off);
  if (l == 0) cvec[j] = s;
}

// ========================= bf16 helpers (D1) =========================
template <int S>
__device__ __forceinline__ void ldAT(bf16x8 (&af)[4][2], const u16* mat, int wr, int lr, int hi) {
  #pragma unroll
  for (int m = 0; m < 4; ++m)
    #pragma unroll
    for (int e = 0; e < 2; ++e) {
      int row = wr * 128 + S * 64 + m * 16 + lr;
      int c = (e * 4 + hi) ^ (lr & 7);
      af[m][e] = *(const bf16x8*)&mat[row * 64 + c * 8];
    }
}
template <int S>
__device__ __forceinline__ void ldBT(bf16x8 (&bq)[2][2][2], const u16* mat, int wc, int lr, int hi) {
  #pragma unroll
  for (int f = 0; f < 2; ++f)
    #pragma unroll
    for (int e = 0; e < 2; ++e) {
      int row = wc * 64 + S * 32 + f * 16 + lr;
      int c = (e * 4 + hi) ^ (lr & 7);
      bq[S][f][e] = *(const bf16x8*)&mat[row * 64 + c * 8];
    }
}
template <int MS, int NS>
__device__ __forceinline__ void quadT(f32x4 (&acc)[8][4], bf16x8 (&af)[4][2], bf16x8 (&bq)[2][2][2]) {
  __builtin_amdgcn_s_setprio(1);
  #pragma unroll
  for (int m = 0; m < 4; ++m)
    #pragma unroll
    for (int f = 0; f < 2; ++f)
      #pragma unroll
      for (int e = 0; e < 2; ++e)
        acc[MS * 4 + m][NS * 2 + f] = __builtin_amdgcn_mfma_f32_16x16x32_bf16(
            af[m][e], bq[NS][f][e], acc[MS * 4 + m][NS * 2 + f], 0, 0, 0);
  __builtin_amdgcn_s_setprio(0);
}

// ========================= fp8 8-phase GEMM =========================
__device__ __forceinline__ void stageL8(const u8* __restrict__ src, u8* dstmat, int w, int lane) {
  #pragma unroll
  for (int i = 0; i < 2; ++i) {
    const u8* g = src + (size_t)((i * 512 + w * 64 + lane) << 4);
    u8* l = dstmat + (size_t)((i * 512 + w * 64) << 4);
    GLDS(g, l);
  }
}
template <int S>
__device__ __forceinline__ void ldAT8(long (&af)[4][2], const u8* mat, int wr, int lr, int hi) {
  #pragma unroll
  for (int m = 0; m < 4; ++m)
    #pragma unroll
    for (int e = 0; e < 2; ++e) {
      int row = wr * 128 + S * 64 + m * 16 + lr;
      int c = e * 32 + hi * 8;
      int ch = (c >> 4) ^ FSWZ(row);
      af[m][e] = *(const long*)&mat[row * 64 + ch * 16 + ((hi & 1) << 3)];
    }
}
template <int S>
__device__ __forceinline__ void ldBT8(long (&bq)[2][2][2], const u8* mat, int wc, int lr, int hi) {
  #pragma unroll
  for (int f = 0; f < 2; ++f)
    #pragma unroll
    for (int e = 0; e < 2; ++e) {
      int row = wc * 64 + S * 32 + f * 16 + lr;
      int c = e * 32 + hi * 8;
      int ch = (c >> 4) ^ FSWZ(row);
      bq[S][f][e] = *(const long*)&mat[row * 64 + ch * 16 + ((hi & 1) << 3)];
    }
}
template <int MS, int NS>
__device__ __forceinline__ void quadT8(f32x4 (&acc)[8][4], long (&af)[4][2], long (&bq)[2][2][2]) {
  __builtin_amdgcn_s_setprio(1);
  #pragma unroll
  for (int m = 0; m < 4; ++m)
    #pragma unroll
    for (int f = 0; f < 2; ++f)
      #pragma unroll
      for (int e = 0; e < 2; ++e)
        acc[MS * 4 + m][NS * 2 + f] = __builtin_amdgcn_mfma_f32_16x16x32_fp8_fp8(
            af[m][e], bq[NS][f][e], acc[MS * 4 + m][NS * 2 + f], 0, 0, 0);
  __builtin_amdgcn_s_setprio(0);
}

template <int STG, int VW>
__device__ __forceinline__ void ktile8(f32x4 (&acc)[8][4], long (&af)[4][2], long (&bq)[2][2][2],
                                       const u8* lA, const u8* lB,
                                       const u8* stA, const u8* stB, u8* sdA, u8* sdB,
                                       int w, int lane, int wr, int wc, int lr, int hi) {
  ldAT8<0>(af, lA, wr, lr, hi); ldBT8<0>(bq, lB, wc, lr, hi);
  SCHED0(); SBAR(); LGKM0(); SCHED0();
  quadT8<0, 0>(acc, af, bq);
  SCHED0(); SBAR();
  ldBT8<1>(bq, lB, wc, lr, hi);
  SCHED0(); SBAR(); LGKM0(); SCHED0();
  quadT8<0, 1>(acc, af, bq);
  SCHED0(); SBAR();
  ldAT8<1>(af, lA, wr, lr, hi);
  if (STG) stageL8(stB, sdB, w, lane);
  SCHED0(); SBAR(); LGKM0(); SCHED0();
  quadT8<1, 1>(acc, af, bq);
  SCHED0(); SBAR();
  if (STG) stageL8(stA, sdA, w, lane);
  SCHED0(); SBAR();
  quadT8<1, 0>(acc, af, bq);
  SCHED0();
  if (VW == 4) { VM4(); } else if (VW == 0) { VM0(); }
  SCHED0(); SBAR();
}

template <int ACT, int OMODE, bool NCHK>  // OMODE: 0 f32 rm via LDS, 1 fp8 tiled via LDS
__global__ __launch_bounds__(512, 2)
void gemm256f8(const u8* __restrict__ A, const u8* __restrict__ Bm,
               const float* __restrict__ bias, float* __restrict__ Cf,
               u8* __restrict__ Cb, int M, int N, int K, int ldc, int ntiles) {
  __shared__ __attribute__((aligned(128))) u8 lds[2][2][256 * 64];  // 64 KiB
  const int tid  = threadIdx.x;
  const int lane = tid & 63;
  const int w    = tid >> 6;
  const int wr   = w >> 2, wc = w & 3;
  const int lr   = lane & 15, hi = lane >> 4;

  int nwg = gridDim.x, cpx = nwg >> 3, b = blockIdx.x;
  int sb = (b & 7) * cpx + (b >> 3);
  int tm = sb / ntiles, tn = sb % ntiles;

  const int NT = K >> 6;
  const u8* Ap = A + (size_t)tm * NT * 16384;
  const u8* Bp = Bm + (size_t)tn * NT * 16384;

  f32x4 acc[8][4] = {};
  long af[4][2], bq[2][2][2];

  stageL8(Ap + 0 * 16384, &lds[0][0][0], w, lane);
  stageL8(Bp + 0 * 16384, &lds[0][1][0], w, lane);
  stageL8(Ap + 1 * 16384, &lds[1][0][0], w, lane);
  stageL8(Bp + 1 * 16384, &lds[1][1][0], w, lane);
  VM4(); SCHED0(); SBAR();

  for (int t = 0; t < NT - 2; ++t) {
    const int bufi = t & 1;
    ktile8<1, 4>(acc, af, bq, &lds[bufi][0][0], &lds[bufi][1][0],
                 Ap + (size_t)(t + 2) * 16384, Bp + (size_t)(t + 2) * 16384,
                 &lds[bufi][0][0], &lds[bufi][1][0], w, lane, wr, wc, lr, hi);
  }
  {
    const int bufi = (NT - 2) & 1;
    ktile8<0, 0>(acc, af, bq, &lds[bufi][0][0], &lds[bufi][1][0],
                 nullptr, nullptr, nullptr, nullptr, w, lane, wr, wc, lr, hi);
  }
  {
    const int bufi = (NT - 1) & 1;
    ktile8<0, -1>(acc, af, bq, &lds[bufi][0][0], &lds[bufi][1][0],
                  nullptr, nullptr, nullptr, nullptr, w, lane, wr, wc, lr, hi);
  }

  const int c0 = tn * 256 + wc * 64;
  float bv[4];
  #pragma unroll
  for (int n = 0; n < 4; ++n) {
    int col = c0 + n * 16 + lr;
    bv[n] = (!NCHK || col < N) ? bias[col] : 0.f;
  }

  if (OMODE == 1) {
    u8* lf8 = &lds[0][0][0];   // 64 KB repack in consumer fp8-tiled layout
    #pragma unroll
    for (int m = 0; m < 8; ++m)
      #pragma unroll
      for (int j = 0; j < 4; ++j) {
        int row = wr * 128 + m * 16 + hi * 4 + j;
        #pragma unroll
        for (int n = 0; n < 4; ++n) {
          int col = wc * 64 + n * 16 + lr;
          float v = acc[m][n][j] + bv[n];
          if (ACT == 1) v = fmaxf(v, 0.f);
          lf8[(col >> 6) * 16384 + (row << 6) + ((((col >> 4) & 3) ^ FSWZ(row)) << 4) + (col & 15)] = f2fp8(v);
        }
      }
    __syncthreads();
    u8* dst = Cb + ((size_t)tm * (ldc >> 6) + tn * 4) * 16384;
    #pragma unroll
    for (int it = 0; it < 8; ++it) {
      int idx = it * 512 + tid;
      *(int4*)&dst[idx * 16] = *(const int4*)&lf8[idx * 16];
    }
  } else {
    // f32 row-major via LDS, 4 passes of 64 rows; hi<<4 XOR kills write conflicts
    float* lf = (float*)&lds[0][0][0];
    const int r0 = tm * 256;
    #pragma unroll
    for (int p = 0; p < 4; ++p) {
      __syncthreads();
      if (wr == (p >> 1)) {
        #pragma unroll
        for (int mm = 0; mm < 4; ++mm) {
          int m = (p & 1) * 4 + mm;
          #pragma unroll
          for (int j = 0; j < 4; ++j) {
            int lrow = m * 16 + hi * 4 + j - (p & 1) * 64;  // 0..63
            #pragma unroll
            for (int n = 0; n < 4; ++n) {
              int col = wc * 64 + n * 16 + lr;
              float v = acc[m][n][j] + bv[n];
              if (ACT == 1) v = fmaxf(v, 0.f);
              if (ACT == 2) v = 1.f / (1.f + __expf(-v));
              lf[lrow * 256 + (col ^ (((lrow >> 2) & 3) << 4))] = v;
            }
          }
        }
      }
      __syncthreads();
      #pragma unroll
      for (int it = 0; it < 8; ++it) {
        int idx = it * 512 + tid;
        int lrow = idx >> 6, c16 = idx & 63;
        int gc = tn * 256 + c16 * 4;
        if (!NCHK || gc < N) {
          f32x4 val = *(const f32x4*)&lf[lrow * 256 + ((c16 * 4) ^ (((lrow >> 2) & 3) << 4))];
          *(f32x4*)&Cf[(size_t)(r0 + p * 64 + lrow) * ldc + gc] = val;
        }
      }
    }
  }
}

// ========================= D1: bf16 K=64, fp8-tiled out =========================
__global__ __launch_bounds__(512, 2)
void gemm_d1(const u16* __restrict__ A, const u16* __restrict__ Bm,
             const float* __restrict__ bias, u8* __restrict__ Cb) {
  __shared__ __attribute__((aligned(128))) u16 ls[2][256 * 64];  // 64 KiB
  const int tid  = threadIdx.x;
  const int lane = tid & 63;
  const int w    = tid >> 6;
  const int wr   = w >> 2, wc = w & 3;
  const int lr   = lane & 15, hi = lane >> 4;

  int b = blockIdx.x;
  int sb = (b & 7) * 64 + (b >> 3);
  int tm = sb >> 2, tn = sb & 3;

  const u16* Ap = A + (size_t)tm * 256 * 64;
  const u16* Bp = Bm + (size_t)tn * 256 * 64;
  #pragma unroll
  for (int i = 0; i < 4; ++i)
    GLDS(Ap + ((i * 512 + w * 64 + lane) << 3), (u16*)&ls[0][0] + ((i * 512 + w * 64) << 3));
  #pragma unroll
  for (int i = 0; i < 4; ++i)
    GLDS(Bp + ((i * 512 + w * 64 + lane) << 3), (u16*)&ls[1][0] + ((i * 512 + w * 64) << 3));
  VM0(); SBAR();

  bf16x8 af0[4][2], af1[4][2], bq[2][2][2];
  ldAT<0>(af0, &ls[0][0], wr, lr, hi);
  ldAT<1>(af1, &ls[0][0], wr, lr, hi);
  ldBT<0>(bq, &ls[1][0], wc, lr, hi);
  ldBT<1>(bq, &ls[1][0], wc, lr, hi);
  LGKM0(); SCHED0();
  f32x4 acc[8][4] = {};
  quadT<0, 0>(acc, af0, bq); quadT<0, 1>(acc, af0, bq);
  quadT<1, 0>(acc, af1, bq); quadT<1, 1>(acc, af1, bq);
  __syncthreads();

  float bv[4];
  #pragma unroll
  for (int n = 0; n < 4; ++n) bv[n] = bias[tn * 256 + wc * 64 + n * 16 + lr];
  u8* lf8 = (u8*)&ls[0][0];
  #pragma unroll
  for (int m = 0; m < 8; ++m)
    #pragma unroll
    for (int j = 0; j < 4; ++j) {
      int row = wr * 128 + m * 16 + hi * 4 + j;
      #pragma unroll
      for (int n = 0; n < 4; ++n) {
        int col = wc * 64 + n * 16 + lr;
        float v = fmaxf(acc[m][n][j] + bv[n], 0.f);
        lf8[(col >> 6) * 16384 + (row << 6) + ((((col >> 4) & 3) ^ FSWZ(row)) << 4) + (col & 15)] = f2fp8(v);
      }
    }
  __syncthreads();
  u8* dst = Cb + ((size_t)tm * 16 + tn * 4) * 16384;
  #pragma unroll
  for (int it = 0; it < 8; ++it) {
    int idx = it * 512 + tid;
    *(int4*)&dst[idx * 16] = *(const int4*)&lf8[idx * 16];
  }
}

// ========================= fused z + VQ =========================
__global__ __launch_bounds__(256, 1)
void z_vq(const u8* __restrict__ Atiled,       // hB fp8 tiled, K=1024
          const u8* __restrict__ Wrm,          // We3 fp8 row-major [64][1024]
          const float* __restrict__ be3,
          const u16* __restrict__ ebf,         // emb bf16 rm64-swz [512][64]
          const float* __restrict__ cvec,
          u16* __restrict__ qb, float* __restrict__ lossacc) {
  __shared__ u8 lsA[2][128 * 64];   // 16 KB
  __shared__ u8 lsW[2][64 * 64];    // 8 KB
  __shared__ u16 embl[512 * 64];    // 64 KB
  __shared__ float zls[128 * 68];
  __shared__ int bidxl[128];

  const int t = threadIdx.x;
  const int lane = t & 63;
  const int w = t >> 6;
  const int lr = lane & 15, hi = lane >> 4;
  const int tm = blockIdx.x;

  #pragma unroll
  for (int i = 0; i < 16; ++i) {
    const u16* g = ebf + (size_t)((i * 256 + t) << 3);
    u16* l = embl + (size_t)((i * 256 + w * 64) << 3);
    GLDS(g, l);
  }

  const size_t abase0 = ((size_t)(tm >> 1) * 16) * 16384 + (size_t)(tm & 1) * 8192;
  auto stageA = [&](int kt, int buf) {
    #pragma unroll
    for (int i = 0; i < 2; ++i) {
      const u8* g = Atiled + abase0 + (size_t)kt * 16384 + ((i * 256 + t) << 4);
      u8* l = lsA[buf] + ((i * 256 + w * 64) << 4);
      GLDS(g, l);
    }
  };
  auto stageW = [&](int kt, int buf) {
    int row = w * 16 + (lane >> 2), p = lane & 3;
    const u8* g = Wrm + (size_t)row * 1024 + kt * 64 + ((p ^ FSWZ(row)) << 4);
    u8* l = lsW[buf] + ((w * 64) << 4);
    GLDS(g, l);
  };

  f32x4 acc[2][4] = {};
  stageA(0, 0); stageW(0, 0);
  stageA(1, 1); stageW(1, 1);
  for (int kt = 0; kt < 16; ++kt) {
    const int bf = kt & 1;
    if (kt < 15) { VM3(); } else { VM0(); }
    __syncthreads();
    #pragma unroll
    for (int kk = 0; kk < 64; kk += 32) {
      long af[2], bfr[4];
      #pragma unroll
      for (int m = 0; m < 2; ++m) {
        int row = w * 32 + m * 16 + lr;
        int c = kk + hi * 8;
        int ch = (c >> 4) ^ FSWZ(row);
        af[m] = *(const long*)&lsA[bf][row * 64 + ch * 16 + ((hi & 1) << 3)];
      }
      #pragma unroll
      for (int n = 0; n < 4; ++n) {
        int row = n * 16 + lr;
        int c = kk + hi * 8;
        int ch = (c >> 4) ^ FSWZ(row);
        bfr[n] = *(const long*)&lsW[bf][row * 64 + ch * 16 + ((hi & 1) << 3)];
      }
      #pragma unroll
      for (int m = 0; m < 2; ++m)
        #pragma unroll
        for (int n = 0; n < 4; ++n)
          acc[m][n] = __builtin_amdgcn_mfma_f32_16x16x32_fp8_fp8(af[m], bfr[n], acc[m][n], 0, 0, 0);
    }
    __syncthreads();
    if (kt + 2 < 16) { stageA(kt + 2, bf); stageW(kt + 2, bf); }
  }

  #pragma unroll
  for (int m = 0; m < 2; ++m)
    #pragma unroll
    for (int j = 0; j < 4; ++j) {
      int row = w * 32 + m * 16 + hi * 4 + j;
      #pragma unroll
      for (int n = 0; n < 4; ++n) {
        int col = n * 16 + lr;
        zls[row * 68 + col] = acc[m][n][j] + be3[col];
      }
    }
  __syncthreads();

  bf16x8 azf[2][2];
  #pragma unroll
  for (int rt = 0; rt < 2; ++rt)
    #pragma unroll
    for (int kf = 0; kf < 2; ++kf) {
      int row = w * 32 + rt * 16 + lr;
      union { bf16x8 v; u16 u[8]; } pk;
      #pragma unroll
      for (int e = 0; e < 8; ++e)
        pk.u[e] = f2bf(zls[row * 68 + kf * 32 + hi * 8 + e]);
      azf[rt][kf] = pk.v;
    }

  float bvv[2][4]; int bii[2][4];
  #pragma unroll
  for (int rt = 0; rt < 2; ++rt)
    #pragma unroll
    for (int j = 0; j < 4; ++j) { bvv[rt][j] = 3.4e38f; bii[rt][j] = 0; }

  for (int ct = 0; ct < 32; ++ct) {
    bf16x8 bqf[2];
    #pragma unroll
    for (int kf = 0; kf < 2; ++kf) {
      int row = ct * 16 + lr;
      int ch = (kf * 4 + hi) ^ (row & 7);
      bqf[kf] = *(const bf16x8*)&embl[row * 64 + ch * 8];
    }
    float cv = cvec[ct * 16 + lr];
    #pragma unroll
    for (int rt = 0; rt < 2; ++rt) {
      f32x4 sc = {};
      sc = __builtin_amdgcn_mfma_f32_16x16x32_bf16(azf[rt][0], bqf[0], sc, 0, 0, 0);
      sc = __builtin_amdgcn_mfma_f32_16x16x32_bf16(azf[rt][1], bqf[1], sc, 0, 0, 0);
      int code = ct * 16 + lr;
      #pragma unroll
      for (int j = 0; j < 4; ++j) {
        float d = cv - sc[j];
        if (d < bvv[rt][j]) { bvv[rt][j] = d; bii[rt][j] = code; }
      }
    }
  }
  #pragma unroll
  for (int off = 1; off < 16; off <<= 1) {
    #pragma unroll
    for (int rt = 0; rt < 2; ++rt)
      #pragma unroll
      for (int j = 0; j < 4; ++j) {
        float ov = __shfl_xor(bvv[rt][j], off);
        int   oi = __shfl_xor(bii[rt][j], off);
        if (ov < bvv[rt][j] || (ov == bvv[rt][j] && oi < bii[rt][j])) {
          bvv[rt][j] = ov; bii[rt][j] = oi;
        }
      }
  }
  if (lr == 0) {
    #pragma unroll
    for (int rt = 0; rt < 2; ++rt)
      #pragma unroll
      for (int j = 0; j < 4; ++j)
        bidxl[w * 32 + rt * 16 + hi * 4 + j] = bii[rt][j];
  }
  __syncthreads();

  const int gr0 = tm * 128;
  float ls = 0.f;
  #pragma unroll 4
  for (int r8 = 0; r8 < 32; ++r8) {
    int row = w * 32 + r8;
    int bi = bidxl[row];
    u16 qu = embl[bi * 64 + (((lane >> 3) ^ (bi & 7)) << 3) + (lane & 7)];
    float qf = bf2f(qu);
    float d = qf - zls[row * 68 + lane];
    ls += d * d;
    qb[(size_t)(gr0 + row) * 64 + (((lane >> 3) ^ (row & 7)) << 3) + (lane & 7)] = qu;
  }
  #pragma unroll
  for (int off = 32; off > 0; off >>= 1) ls += __shfl_down(ls, off);
  if (lane == 0) atomicAdd(lossacc, ls);
}

__global__ void loss_final(const float* __restrict__ acc, float* __restrict__ o, float denom) {
  o[0] = acc[0] * 1.25f / denom;
}

// ---------- launch ----------
extern "C" void kernel_launch(void* const* d_in, const int* in_sizes, int n_in,
                              void* d_out, int out_size, void* d_ws, size_t ws_size,
                              hipStream_t stream) {
  const float* x   = (const float*)d_in[0];
  const float* emb = (const float*)d_in[1];
  const float* We1 = (const float*)d_in[2];
  const float* be1 = (const float*)d_in[3];
  const float* We2 = (const float*)d_in[4];
  const float* be2 = (const float*)d_in[5];
  const float* We3 = (const float*)d_in[6];
  const float* be3 = (const float*)d_in[7];
  const float* Wd1 = (const float*)d_in[8];
  const float* bd1 = (const float*)d_in[9];
  const float* Wd2 = (const float*)d_in[10];
  const float* bd2 = (const float*)d_in[11];
  const float* Wd3 = (const float*)d_in[12];
  const float* bd3 = (const float*)d_in[13];

  const int Bn = in_sizes[0] / NIN;              // 32768
  float* out = (float*)d_out;
  float* out_loss = out + (size_t)Bn * NIN;

  char* ws = (char*)d_ws;
  size_t off = 0;
  auto take = [&](size_t bytes) { char* p = ws + off; off += (bytes + 255) & ~(size_t)255; return p; };

  u8*    xpad8 = (u8*)take((size_t)Bn * NINP);     // fp8 tiled
  u8*    hA8   = (u8*)take((size_t)Bn * NH);       // fp8 tiled: h1 -> h3
  u8*    hB8   = (u8*)take((size_t)Bn * NH);       // fp8 tiled: h2 -> h4
  u16*   qb    = (u16*)take((size_t)Bn * ND * 2);  // bf16 rm64-swz
  u8*    we1p8 = (u8*)take((size_t)NH * NINP);     // fp8 tiled
  u8*    we2b8 = (u8*)take((size_t)NH * NH);       // fp8 tiled
  u8*    we3r8 = (u8*)take((size_t)64 * NH);       // fp8 row-major
  u16*   wd1b  = (u16*)take((size_t)NH * ND * 2);  // bf16 rm64-swz
  u8*    wd2b8 = (u8*)take((size_t)NH * NH);       // fp8 tiled
  u8*    wd3p8 = (u8*)take((size_t)NOUTP * NH);    // fp8 tiled, rows 784+ zero
  u16*   embb  = (u16*)take((size_t)NE * ND * 2);  // bf16 rm64-swz
  float* cvec  = (float*)take(NE * 4);
  float* lossa = (float*)take(4);

  hipMemsetAsync(lossa, 0, 4, stream);

  cast_tiled8<<<dim3(1, Bn),    256, 0, stream>>>(x,   xpad8, Bn,  NIN, NINP);
  cast_tiled8<<<dim3(1, NH),    256, 0, stream>>>(We1, we1p8, NH,  NIN, NINP);
  cast_tiled8<<<dim3(1, NH),    256, 0, stream>>>(We2, we2b8, NH,  NH,  NH);
  cast_rm8   <<<dim3(1, 64),    256, 0, stream>>>(We3, we3r8, 64,  NH);
  cast_rm64swz<<<NH, 64, 0, stream>>>(Wd1, wd1b, NH);
  cast_tiled8<<<dim3(1, NH),    256, 0, stream>>>(Wd2, wd2b8, NH,  NH,  NH);
  cast_tiled8<<<dim3(1, NOUTP), 256, 0, stream>>>(Wd3, wd3p8, NIN, NH,  NH);
  emb_prep<<<NE, 64, 0, stream>>>(emb, embb, cvec);

  // encoder
  gemm256f8<1,1,false><<<512, 512, 0, stream>>>(xpad8, we1p8, be1, nullptr, hA8, Bn, NH, NINP, NH, 4);
  gemm256f8<1,1,false><<<512, 512, 0, stream>>>(hA8, we2b8, be2, nullptr, hB8, Bn, NH, NH, NH, 4);
  // fused z + VQ
  z_vq<<<Bn / 128, 256, 0, stream>>>(hB8, we3r8, be3, embb, cvec, qb, lossa);
  // decoder
  gemm_d1<<<512, 512, 0, stream>>>(qb, wd1b, bd1, hA8);
  gemm256f8<1,1,false><<<512, 512, 0, stream>>>(hA8, wd2b8, bd2, nullptr, hB8, Bn, NH, NH, NH, 4);
  gemm256f8<2,0,true ><<<512, 512, 0, stream>>>(hB8, wd3p8, bd3, out, nullptr, Bn, NIN, NH, NIN, 4);

  loss_final<<<1, 1, 0, stream>>>(lossa, out_loss, (float)Bn * ND);
}

// Round 8
// 310.043 us; speedup vs baseline: 1.5273x; 1.5273x over previous
//
#include <hip/hip_runtime.h>
#include <stdint.h>
#include <stddef.h>

typedef __bf16 bf16x8 __attribute__((ext_vector_type(8)));
typedef float  f32x4  __attribute__((ext_vector_type(4)));
typedef unsigned short u16;
typedef unsigned char  u8;

#define NIN   784
#define NINP  896
#define NH    1024
#define NE    512
#define ND    64
#define NOUTP 1024

#define BAR()   asm volatile("s_barrier" ::: "memory")
#define LGKM0() asm volatile("s_waitcnt lgkmcnt(0)" ::: "memory")
#define VM4()   asm volatile("s_waitcnt vmcnt(4)" ::: "memory")
#define VM3()   asm volatile("s_waitcnt vmcnt(3)" ::: "memory")
#define VM0()   asm volatile("s_waitcnt vmcnt(0)" ::: "memory")
#define FSWZ(r) (((r) ^ ((r) >> 2)) & 3)
#define GLDS(g, l) __builtin_amdgcn_global_load_lds((__attribute__((address_space(1))) void*)(g), (__attribute__((address_space(3))) void*)(l), 16, 0, 0)

static __device__ __forceinline__ u16 f2bf(float f) {
  union { float f; unsigned u; } v; v.f = f;
  unsigned r = v.u + 0x7fffu + ((v.u >> 16) & 1u);
  return (u16)(r >> 16);
}
static __device__ __forceinline__ float bf2f(u16 b) {
  union { unsigned u; float f; } v; v.u = ((unsigned)b) << 16; return v.f;
}
// HW fp8 (e4m3) conversion
static __device__ __forceinline__ unsigned pack4fp8(float a, float b, float c, float d) {
  unsigned p;
  asm("v_cvt_pk_fp8_f32 %0, %1, %2" : "=v"(p) : "v"(a), "v"(b));
  asm("v_cvt_pk_fp8_f32 %0, %1, %2 op_sel:[0,0,1]" : "+v"(p) : "v"(c), "v"(d));
  return p;
}
static __device__ __forceinline__ u8 f2fp8(float a) {
  unsigned p;
  asm("v_cvt_pk_fp8_f32 %0, %1, %2" : "=v"(p) : "v"(a), "v"(a));
  return (u8)(p & 0xff);
}

// fp8 tiled layout: blk=(r>>8)*(Cp>>6)+(c>>6) [16384 B],
//   off = (r&255)*64 + ((((c>>4)&3)^FSWZ(r))<<4) + (c&15)

// ---------- casts ----------
__global__ void cast_tiled8(const float* __restrict__ src, u8* __restrict__ dst,
                            int R, int C, int Cp) {
  int r = blockIdx.y;
  int c4 = (blockIdx.x * blockDim.x + threadIdx.x) * 4;
  if (c4 >= Cp) return;
  unsigned o = 0;
  if (r < R && c4 < C) {
    const float4 v = *(const float4*)&src[(size_t)r * C + c4];
    o = pack4fp8(v.x, v.y, v.z, v.w);
  }
  size_t off = ((size_t)(r >> 8) * (Cp >> 6) + (c4 >> 6)) * 16384
             + ((r & 255) << 6) + ((((c4 >> 4) & 3) ^ FSWZ(r)) << 4) + (c4 & 15);
  *(unsigned*)&dst[off] = o;
}

__global__ void cast_rm8(const float* __restrict__ src, u8* __restrict__ dst, int R, int C) {
  int r = blockIdx.y;
  int c4 = (blockIdx.x * blockDim.x + threadIdx.x) * 4;
  if (c4 >= C) return;
  const float4 v = *(const float4*)&src[(size_t)r * C + c4];
  *(unsigned*)&dst[(size_t)r * C + c4] = pack4fp8(v.x, v.y, v.z, v.w);
}

__global__ void emb_prep(const float* __restrict__ emb, u16* __restrict__ ebf,
                         float* __restrict__ cvec) {
  int j = blockIdx.x, l = threadIdx.x;
  float v = emb[j * ND + l];
  ebf[j * 64 + (((l >> 3) ^ (j & 7)) << 3) + (l & 7)] = f2bf(v);
  float s = v * v;
  #pragma unroll
  for (int off = 32; off > 0; off >>= 1) s += __shfl_down(s, off);
  if (l == 0) cvec[j] = s;
}

// =========================================================================
// 128x128-tile fp8 GEMM: 4 waves, 2-deep prefetch, 2 raw barriers / K-tile.
// Operands in fp8-tiled layout (swizzle baked). acc = 64 VGPR/lane -> high TLP.
// OMODE: 0 = f32 row-major out, 1 = fp8 tiled out.  Handles NT==1.
// =========================================================================
template <int ACT, int OMODE, bool NCHK>
__global__ __launch_bounds__(256, 3)
void gemm128f8(const u8* __restrict__ A, const u8* __restrict__ Bm,
               const float* __restrict__ bias, float* __restrict__ Cf,
               u8* __restrict__ Cb, int N, int K, int ldc, int ntiles) {
  __shared__ __attribute__((aligned(128))) u8 lds[32768];  // A:2x8K | B:2x8K
  const int tid = threadIdx.x, lane = tid & 63, w = tid >> 6;
  const int wr = w >> 1, wc = w & 1;
  const int lr = lane & 15, hi = lane >> 4;

  int nwg = gridDim.x, cpx = nwg >> 3, b = blockIdx.x;
  int sb = (b & 7) * cpx + (b >> 3);
  int tm = sb / ntiles, tn = sb % ntiles;

  const int NT = K >> 6;
  const u8* Ap = A + (size_t)(tm >> 1) * NT * 16384 + (size_t)(tm & 1) * 8192;
  const u8* Bp = Bm + (size_t)(tn >> 1) * NT * 16384 + (size_t)(tn & 1) * 8192;

  auto stage = [&](int t, int buf) {
    #pragma unroll
    for (int i = 0; i < 2; ++i)
      GLDS(Ap + (size_t)t * 16384 + ((i * 256 + tid) << 4),
           lds + buf * 8192 + ((i * 256 + w * 64) << 4));
    #pragma unroll
    for (int i = 0; i < 2; ++i)
      GLDS(Bp + (size_t)t * 16384 + ((i * 256 + tid) << 4),
           lds + 16384 + buf * 8192 + ((i * 256 + w * 64) << 4));
  };

  f32x4 acc[4][4] = {};
  stage(0, 0);
  if (NT > 1) stage(1, 1);

  for (int t = 0; t < NT; ++t) {
    const int buf = t & 1;
    if (t + 1 < NT) { VM4(); } else { VM0(); }
    BAR();                                   // tile t resident for all waves
    const u8* lA = lds + buf * 8192;
    const u8* lB = lds + 16384 + buf * 8192;
    long af[4][2], bfr[4][2];
    #pragma unroll
    for (int m = 0; m < 4; ++m) {
      int row = wr * 64 + m * 16 + lr;
      #pragma unroll
      for (int e = 0; e < 2; ++e) {
        int ch = (e * 2 + (hi >> 1)) ^ FSWZ(row);
        af[m][e] = *(const long*)&lA[row * 64 + ch * 16 + ((hi & 1) << 3)];
      }
    }
    #pragma unroll
    for (int n = 0; n < 4; ++n) {
      int row = wc * 64 + n * 16 + lr;
      #pragma unroll
      for (int e = 0; e < 2; ++e) {
        int ch = (e * 2 + (hi >> 1)) ^ FSWZ(row);
        bfr[n][e] = *(const long*)&lB[row * 64 + ch * 16 + ((hi & 1) << 3)];
      }
    }
    LGKM0();
    BAR();                                   // all waves done reading buf
    if (t + 2 < NT) stage(t + 2, buf);       // overwrite under MFMA cover
    #pragma unroll
    for (int m = 0; m < 4; ++m)
      #pragma unroll
      for (int n = 0; n < 4; ++n)
        #pragma unroll
        for (int e = 0; e < 2; ++e)
          acc[m][n] = __builtin_amdgcn_mfma_f32_16x16x32_fp8_fp8(
              af[m][e], bfr[n][e], acc[m][n], 0, 0, 0);
  }

  // ---- epilogue: f32 -> LDS (dword, swizzled) -> convert/store, 2 passes ----
  const int c0 = wc * 64;
  float bv[4];
  #pragma unroll
  for (int n = 0; n < 4; ++n) {
    int col = tn * 128 + c0 + n * 16 + lr;
    bv[n] = (!NCHK || col < N) ? bias[col] : 0.f;
  }
  float* lf = (float*)lds;                   // [64][128] f32 = 32 KB
  #pragma unroll
  for (int p = 0; p < 2; ++p) {
    __syncthreads();
    if (wr == p) {
      #pragma unroll
      for (int m = 0; m < 4; ++m)
        #pragma unroll
        for (int j = 0; j < 4; ++j) {
          int lrow = m * 16 + hi * 4 + j;    // 0..63
          #pragma unroll
          for (int n = 0; n < 4; ++n) {
            int col = c0 + n * 16 + lr;      // 0..127
            float v = acc[m][n][j] + bv[n];
            if (ACT == 1) v = fmaxf(v, 0.f);
            if (ACT == 2) v = 1.f / (1.f + __expf(-v));
            lf[lrow * 128 + (((col >> 2) ^ (lrow & 31)) << 2) + (col & 3)] = v;
          }
        }
    }
    __syncthreads();
    #pragma unroll
    for (int it = 0; it < 2; ++it) {
      int idx = it * 256 + tid;              // 512 chunks of 16 cols
      int lrow = idx >> 3, cc = idx & 7;
      f32x4 q[4];
      #pragma unroll
      for (int s = 0; s < 4; ++s)
        q[s] = *(const f32x4*)&lf[lrow * 128 + (((cc * 4 + s) ^ (lrow & 31)) << 2)];
      int R = tm * 128 + p * 64 + lrow;
      if (OMODE == 1) {
        int C = tn * 128 + cc * 16;
        int4 o;
        o.x = pack4fp8(q[0][0], q[0][1], q[0][2], q[0][3]);
        o.y = pack4fp8(q[1][0], q[1][1], q[1][2], q[1][3]);
        o.z = pack4fp8(q[2][0], q[2][1], q[2][2], q[2][3]);
        o.w = pack4fp8(q[3][0], q[3][1], q[3][2], q[3][3]);
        size_t off = ((size_t)(R >> 8) * (ldc >> 6) + (C >> 6)) * 16384
                   + ((R & 255) << 6) + ((((C >> 4) & 3) ^ FSWZ(R)) << 4);
        *(int4*)&Cb[off] = o;
      } else {
        int gc = tn * 128 + cc * 16;
        if (!NCHK || gc < N) {
          #pragma unroll
          for (int s = 0; s < 4; ++s)
            *(f32x4*)&Cf[(size_t)R * ldc + gc + s * 4] = q[s];
        }
      }
    }
  }
}

// =========================================================================
// Fused z = hB @ We3^T + be3 ; scores = z @ emb^T ; argmin ; q gather ; loss
// Raw barriers + counted vmcnt (2-deep prefetch actually in flight).
// =========================================================================
__global__ __launch_bounds__(256, 1)
void z_vq(const u8* __restrict__ Atiled,       // hB fp8 tiled, K=1024
          const u8* __restrict__ Wrm,          // We3 fp8 row-major [64][1024]
          const float* __restrict__ be3,
          const u16* __restrict__ ebf,         // emb bf16 rm64-swz [512][64]
          const float* __restrict__ cvec,
          u8* __restrict__ qb8, float* __restrict__ lossacc) {
  __shared__ u8 lsA[2][128 * 64];
  __shared__ u8 lsW[2][64 * 64];
  __shared__ u16 embl[512 * 64];
  __shared__ float zls[128 * 68];
  __shared__ int bidxl[128];

  const int t = threadIdx.x;
  const int lane = t & 63;
  const int w = t >> 6;
  const int lr = lane & 15, hi = lane >> 4;
  const int tm = blockIdx.x;

  #pragma unroll
  for (int i = 0; i < 16; ++i) {
    const u16* g = ebf + (size_t)((i * 256 + t) << 3);
    u16* l = embl + (size_t)((i * 256 + w * 64) << 3);
    GLDS(g, l);
  }

  const size_t abase0 = ((size_t)(tm >> 1) * 16) * 16384 + (size_t)(tm & 1) * 8192;
  auto stageA = [&](int kt, int buf) {
    #pragma unroll
    for (int i = 0; i < 2; ++i) {
      const u8* g = Atiled + abase0 + (size_t)kt * 16384 + ((i * 256 + t) << 4);
      u8* l = lsA[buf] + ((i * 256 + w * 64) << 4);
      GLDS(g, l);
    }
  };
  auto stageW = [&](int kt, int buf) {
    int row = w * 16 + (lane >> 2), p = lane & 3;
    const u8* g = Wrm + (size_t)row * 1024 + kt * 64 + ((p ^ FSWZ(row)) << 4);
    u8* l = lsW[buf] + ((w * 64) << 4);
    GLDS(g, l);
  };

  f32x4 acc[2][4] = {};
  stageA(0, 0); stageW(0, 0);
  stageA(1, 1); stageW(1, 1);
  for (int kt = 0; kt < 16; ++kt) {
    const int bf = kt & 1;
    if (kt < 15) { VM3(); } else { VM0(); }
    BAR();
    #pragma unroll
    for (int kk = 0; kk < 64; kk += 32) {
      long af[2], bfr[4];
      #pragma unroll
      for (int m = 0; m < 2; ++m) {
        int row = w * 32 + m * 16 + lr;
        int ch = ((kk >> 4) + (hi >> 1)) ^ FSWZ(row);
        af[m] = *(const long*)&lsA[bf][row * 64 + ch * 16 + ((hi & 1) << 3)];
      }
      #pragma unroll
      for (int n = 0; n < 4; ++n) {
        int row = n * 16 + lr;
        int ch = ((kk >> 4) + (hi >> 1)) ^ FSWZ(row);
        bfr[n] = *(const long*)&lsW[bf][row * 64 + ch * 16 + ((hi & 1) << 3)];
      }
      #pragma unroll
      for (int m = 0; m < 2; ++m)
        #pragma unroll
        for (int n = 0; n < 4; ++n)
          acc[m][n] = __builtin_amdgcn_mfma_f32_16x16x32_fp8_fp8(af[m], bfr[n], acc[m][n], 0, 0, 0);
    }
    LGKM0();
    BAR();
    if (kt + 2 < 16) { stageA(kt + 2, bf); stageW(kt + 2, bf); }
  }

  #pragma unroll
  for (int m = 0; m < 2; ++m)
    #pragma unroll
    for (int j = 0; j < 4; ++j) {
      int row = w * 32 + m * 16 + hi * 4 + j;
      #pragma unroll
      for (int n = 0; n < 4; ++n) {
        int col = n * 16 + lr;
        zls[row * 68 + col] = acc[m][n][j] + be3[col];
      }
    }
  __syncthreads();

  bf16x8 azf[2][2];
  #pragma unroll
  for (int rt = 0; rt < 2; ++rt)
    #pragma unroll
    for (int kf = 0; kf < 2; ++kf) {
      int row = w * 32 + rt * 16 + lr;
      union { bf16x8 v; u16 u[8]; } pk;
      #pragma unroll
      for (int e = 0; e < 8; ++e)
        pk.u[e] = f2bf(zls[row * 68 + kf * 32 + hi * 8 + e]);
      azf[rt][kf] = pk.v;
    }

  float bvv[2][4]; int bii[2][4];
  #pragma unroll
  for (int rt = 0; rt < 2; ++rt)
    #pragma unroll
    for (int j = 0; j < 4; ++j) { bvv[rt][j] = 3.4e38f; bii[rt][j] = 0; }

  for (int ct = 0; ct < 32; ++ct) {
    bf16x8 bqf[2];
    #pragma unroll
    for (int kf = 0; kf < 2; ++kf) {
      int row = ct * 16 + lr;
      int ch = (kf * 4 + hi) ^ (row & 7);
      bqf[kf] = *(const bf16x8*)&embl[row * 64 + ch * 8];
    }
    float cv = cvec[ct * 16 + lr];
    #pragma unroll
    for (int rt = 0; rt < 2; ++rt) {
      f32x4 sc = {};
      sc = __builtin_amdgcn_mfma_f32_16x16x32_bf16(azf[rt][0], bqf[0], sc, 0, 0, 0);
      sc = __builtin_amdgcn_mfma_f32_16x16x32_bf16(azf[rt][1], bqf[1], sc, 0, 0, 0);
      int code = ct * 16 + lr;
      #pragma unroll
      for (int j = 0; j < 4; ++j) {
        float d = cv - sc[j];
        if (d < bvv[rt][j]) { bvv[rt][j] = d; bii[rt][j] = code; }
      }
    }
  }
  #pragma unroll
  for (int off = 1; off < 16; off <<= 1) {
    #pragma unroll
    for (int rt = 0; rt < 2; ++rt)
      #pragma unroll
      for (int j = 0; j < 4; ++j) {
        float ov = __shfl_xor(bvv[rt][j], off);
        int   oi = __shfl_xor(bii[rt][j], off);
        if (ov < bvv[rt][j] || (ov == bvv[rt][j] && oi < bii[rt][j])) {
          bvv[rt][j] = ov; bii[rt][j] = oi;
        }
      }
  }
  if (lr == 0) {
    #pragma unroll
    for (int rt = 0; rt < 2; ++rt)
      #pragma unroll
      for (int j = 0; j < 4; ++j)
        bidxl[w * 32 + rt * 16 + hi * 4 + j] = bii[rt][j];
  }
  __syncthreads();

  const int gr0 = tm * 128;
  float ls = 0.f;
  #pragma unroll 4
  for (int r8 = 0; r8 < 32; ++r8) {
    int row = w * 32 + r8;
    int bi = bidxl[row];
    u16 qu = embl[bi * 64 + (((lane >> 3) ^ (bi & 7)) << 3) + (lane & 7)];
    float qf = bf2f(qu);
    float d = qf - zls[row * 68 + lane];
    ls += d * d;
    int R = gr0 + row;
    qb8[(size_t)R * 64 + ((((lane >> 4) & 3) ^ FSWZ(R)) << 4) + (lane & 15)] = f2fp8(qf);
  }
  #pragma unroll
  for (int off = 32; off > 0; off >>= 1) ls += __shfl_down(ls, off);
  if (lane == 0) atomicAdd(lossacc, ls);
}

__global__ void loss_final(const float* __restrict__ acc, float* __restrict__ o, float denom) {
  o[0] = acc[0] * 1.25f / denom;
}

// ---------- launch ----------
extern "C" void kernel_launch(void* const* d_in, const int* in_sizes, int n_in,
                              void* d_out, int out_size, void* d_ws, size_t ws_size,
                              hipStream_t stream) {
  const float* x   = (const float*)d_in[0];
  const float* emb = (const float*)d_in[1];
  const float* We1 = (const float*)d_in[2];
  const float* be1 = (const float*)d_in[3];
  const float* We2 = (const float*)d_in[4];
  const float* be2 = (const float*)d_in[5];
  const float* We3 = (const float*)d_in[6];
  const float* be3 = (const float*)d_in[7];
  const float* Wd1 = (const float*)d_in[8];
  const float* bd1 = (const float*)d_in[9];
  const float* Wd2 = (const float*)d_in[10];
  const float* bd2 = (const float*)d_in[11];
  const float* Wd3 = (const float*)d_in[12];
  const float* bd3 = (const float*)d_in[13];

  const int Bn = in_sizes[0] / NIN;              // 32768
  float* out = (float*)d_out;
  float* out_loss = out + (size_t)Bn * NIN;

  char* ws = (char*)d_ws;
  size_t off = 0;
  auto take = [&](size_t bytes) { char* p = ws + off; off += (bytes + 255) & ~(size_t)255; return p; };

  u8*    xpad8 = (u8*)take((size_t)Bn * NINP);     // fp8 tiled
  u8*    hA8   = (u8*)take((size_t)Bn * NH);       // fp8 tiled: h1 -> h3
  u8*    hB8   = (u8*)take((size_t)Bn * NH);       // fp8 tiled: h2 -> h4
  u8*    qb8   = (u8*)take((size_t)Bn * ND);       // fp8 tiled (Cp=64)
  u8*    we1p8 = (u8*)take((size_t)NH * NINP);     // fp8 tiled
  u8*    we2b8 = (u8*)take((size_t)NH * NH);       // fp8 tiled
  u8*    we3r8 = (u8*)take((size_t)64 * NH);       // fp8 row-major
  u8*    wd1b8 = (u8*)take((size_t)NH * ND);       // fp8 tiled (Cp=64)
  u8*    wd2b8 = (u8*)take((size_t)NH * NH);       // fp8 tiled
  u8*    wd3p8 = (u8*)take((size_t)NOUTP * NH);    // fp8 tiled, rows 784+ zero
  u16*   embb  = (u16*)take((size_t)NE * ND * 2);  // bf16 rm64-swz
  float* cvec  = (float*)take(NE * 4);
  float* lossa = (float*)take(4);

  hipMemsetAsync(lossa, 0, 4, stream);

  cast_tiled8<<<dim3(1, Bn),    256, 0, stream>>>(x,   xpad8, Bn,  NIN, NINP);
  cast_tiled8<<<dim3(1, NH),    256, 0, stream>>>(We1, we1p8, NH,  NIN, NINP);
  cast_tiled8<<<dim3(1, NH),    256, 0, stream>>>(We2, we2b8, NH,  NH,  NH);
  cast_rm8   <<<dim3(1, 64),    256, 0, stream>>>(We3, we3r8, 64,  NH);
  cast_tiled8<<<dim3(1, NH),    256, 0, stream>>>(Wd1, wd1b8, NH,  ND,  ND);
  cast_tiled8<<<dim3(1, NH),    256, 0, stream>>>(Wd2, wd2b8, NH,  NH,  NH);
  cast_tiled8<<<dim3(1, NOUTP), 256, 0, stream>>>(Wd3, wd3p8, NIN, NH,  NH);
  emb_prep<<<NE, 64, 0, stream>>>(emb, embb, cvec);

  const int mt = Bn / 128;                       // 256 row-tiles
  // encoder
  gemm128f8<1,1,false><<<mt * 8, 256, 0, stream>>>(xpad8, we1p8, be1, nullptr, hA8, NH, NINP, NH, 8);
  gemm128f8<1,1,false><<<mt * 8, 256, 0, stream>>>(hA8, we2b8, be2, nullptr, hB8, NH, NH, NH, 8);
  // fused z + VQ
  z_vq<<<Bn / 128, 256, 0, stream>>>(hB8, we3r8, be3, embb, cvec, qb8, lossa);
  // decoder
  gemm128f8<1,1,false><<<mt * 8, 256, 0, stream>>>(qb8, wd1b8, bd1, nullptr, hA8, NH, 64, NH, 8);
  gemm128f8<1,1,false><<<mt * 8, 256, 0, stream>>>(hA8, wd2b8, bd2, nullptr, hB8, NH, NH, NH, 8);
  gemm128f8<2,0,true ><<<mt * 7, 256, 0, stream>>>(hB8, wd3p8, bd3, out, nullptr, NIN, NH, NIN, 7);

  loss_final<<<1, 1, 0, stream>>>(lossa, out_loss, (float)Bn * ND);
}

// Round 9
// 264.571 us; speedup vs baseline: 1.7898x; 1.1719x over previous
//
#include <hip/hip_runtime.h>
#include <stdint.h>
#include <stddef.h>

typedef __bf16 bf16x8 __attribute__((ext_vector_type(8)));
typedef float  f32x4  __attribute__((ext_vector_type(4)));
typedef float  f32x16 __attribute__((ext_vector_type(16)));
typedef int    i32x8  __attribute__((ext_vector_type(8)));
typedef unsigned short u16;
typedef unsigned char  u8;

#define NIN   784
#define NINP  896
#define NH    1024
#define NE    512
#define ND    64
#define NOUTP 1024

#define BAR()   asm volatile("s_barrier" ::: "memory")
#define LGKM0() asm volatile("s_waitcnt lgkmcnt(0)" ::: "memory")
#define VM4()   asm volatile("s_waitcnt vmcnt(4)" ::: "memory")
#define VM3()   asm volatile("s_waitcnt vmcnt(3)" ::: "memory")
#define VM0()   asm volatile("s_waitcnt vmcnt(0)" ::: "memory")
#define FSWZ(r) (((r) ^ ((r) >> 2)) & 3)
#define SCL1    0x7F7F7F7F            // E8M0 x4 = 1.0 scales
#define GLDS(g, l) __builtin_amdgcn_global_load_lds((__attribute__((address_space(1))) void*)(g), (__attribute__((address_space(3))) void*)(l), 16, 0, 0)

static __device__ __forceinline__ u16 f2bf(float f) {
  union { float f; unsigned u; } v; v.f = f;
  unsigned r = v.u + 0x7fffu + ((v.u >> 16) & 1u);
  return (u16)(r >> 16);
}
static __device__ __forceinline__ float bf2f(u16 b) {
  union { unsigned u; float f; } v; v.u = ((unsigned)b) << 16; return v.f;
}
static __device__ __forceinline__ unsigned pack4fp8(float a, float b, float c, float d) {
  unsigned p;
  asm("v_cvt_pk_fp8_f32 %0, %1, %2" : "=v"(p) : "v"(a), "v"(b));
  asm("v_cvt_pk_fp8_f32 %0, %1, %2 op_sel:[0,0,1]" : "+v"(p) : "v"(c), "v"(d));
  return p;
}
static __device__ __forceinline__ u8 f2fp8(float a) {
  unsigned p;
  asm("v_cvt_pk_fp8_f32 %0, %1, %2" : "=v"(p) : "v"(a), "v"(a));
  return (u8)(p & 0xff);
}

// fp8 tiled layout: blk=(r>>8)*(Cp>>6)+(c>>6) [16384 B],
//   off = (r&255)*64 + ((((c>>4)&3)^FSWZ(r))<<4) + (c&15)

// ---------- casts ----------
__global__ void cast_tiled8(const float* __restrict__ src, u8* __restrict__ dst,
                            int R, int C, int Cp) {
  int r = blockIdx.y;
  int c4 = (blockIdx.x * blockDim.x + threadIdx.x) * 4;
  if (c4 >= Cp) return;
  unsigned o = 0;
  if (r < R && c4 < C) {
    const float4 v = *(const float4*)&src[(size_t)r * C + c4];
    o = pack4fp8(v.x, v.y, v.z, v.w);
  }
  size_t off = ((size_t)(r >> 8) * (Cp >> 6) + (c4 >> 6)) * 16384
             + ((r & 255) << 6) + ((((c4 >> 4) & 3) ^ FSWZ(r)) << 4) + (c4 & 15);
  *(unsigned*)&dst[off] = o;
}

__global__ void cast_rm8(const float* __restrict__ src, u8* __restrict__ dst, int R, int C) {
  int r = blockIdx.y;
  int c4 = (blockIdx.x * blockDim.x + threadIdx.x) * 4;
  if (c4 >= C) return;
  const float4 v = *(const float4*)&src[(size_t)r * C + c4];
  *(unsigned*)&dst[(size_t)r * C + c4] = pack4fp8(v.x, v.y, v.z, v.w);
}

__global__ void emb_prep(const float* __restrict__ emb, u16* __restrict__ ebf,
                         float* __restrict__ cvec) {
  int j = blockIdx.x, l = threadIdx.x;
  float v = emb[j * ND + l];
  ebf[j * 64 + (((l >> 3) ^ (j & 7)) << 3) + (l & 7)] = f2bf(v);
  float s = v * v;
  #pragma unroll
  for (int off = 32; off > 0; off >>= 1) s += __shfl_down(s, off);
  if (l == 0) cvec[j] = s;
}

// =========================================================================
// 128x128-tile MX-fp8 GEMM: 4 waves, 32x32x64 scaled MFMA (scales = 1.0),
// 2-deep prefetch, 2 raw barriers / K-tile, 3 blocks/CU.
// OMODE: 0 = f32 row-major direct store, 1 = fp8 tiled via LDS. NT==1 ok.
// =========================================================================
template <int ACT, int OMODE, bool NCHK>
__global__ __launch_bounds__(256, 3)
void gemm128mx(const u8* __restrict__ A, const u8* __restrict__ Bm,
               const float* __restrict__ bias, float* __restrict__ Cf,
               u8* __restrict__ Cb, int N, int K, int ldc, int ntiles) {
  __shared__ __attribute__((aligned(128))) u8 lds[32768];  // A:2x8K | B:2x8K
  const int tid = threadIdx.x, lane = tid & 63, w = tid >> 6;
  const int wr = w >> 1, wc = w & 1;
  const int l31 = lane & 31, h = lane >> 5;      // h: k-half selector

  int nwg = gridDim.x, cpx = nwg >> 3, b = blockIdx.x;
  int sb = (b & 7) * cpx + (b >> 3);
  int tm = sb / ntiles, tn = sb % ntiles;

  const int NT = K >> 6;
  const u8* Ap = A + (size_t)(tm >> 1) * NT * 16384 + (size_t)(tm & 1) * 8192;
  const u8* Bp = Bm + (size_t)(tn >> 1) * NT * 16384 + (size_t)(tn & 1) * 8192;

  auto stage = [&](int t, int buf) {
    #pragma unroll
    for (int i = 0; i < 2; ++i)
      GLDS(Ap + (size_t)t * 16384 + ((i * 256 + tid) << 4),
           lds + buf * 8192 + ((i * 256 + w * 64) << 4));
    #pragma unroll
    for (int i = 0; i < 2; ++i)
      GLDS(Bp + (size_t)t * 16384 + ((i * 256 + tid) << 4),
           lds + 16384 + buf * 8192 + ((i * 256 + w * 64) << 4));
  };

  f32x16 acc[2][2] = {};
  stage(0, 0);
  if (NT > 1) stage(1, 1);

  for (int t = 0; t < NT; ++t) {
    const int buf = t & 1;
    if (t + 1 < NT) { VM4(); } else { VM0(); }
    BAR();
    const u8* lA = lds + buf * 8192;
    const u8* lB = lds + 16384 + buf * 8192;
    i32x8 af[2], bf_[2];
    #pragma unroll
    for (int s = 0; s < 2; ++s) {
      int row = wr * 64 + s * 32 + l31;
      int F = FSWZ(row);
      const u8* base = lA + row * 64;
      int4 lo = *(const int4*)&base[(((h << 1)    ) ^ F) << 4];
      int4 hi = *(const int4*)&base[(((h << 1) | 1) ^ F) << 4];
      af[s][0] = lo.x; af[s][1] = lo.y; af[s][2] = lo.z; af[s][3] = lo.w;
      af[s][4] = hi.x; af[s][5] = hi.y; af[s][6] = hi.z; af[s][7] = hi.w;
    }
    #pragma unroll
    for (int s = 0; s < 2; ++s) {
      int row = wc * 64 + s * 32 + l31;
      int F = FSWZ(row);
      const u8* base = lB + row * 64;
      int4 lo = *(const int4*)&base[(((h << 1)    ) ^ F) << 4];
      int4 hi = *(const int4*)&base[(((h << 1) | 1) ^ F) << 4];
      bf_[s][0] = lo.x; bf_[s][1] = lo.y; bf_[s][2] = lo.z; bf_[s][3] = lo.w;
      bf_[s][4] = hi.x; bf_[s][5] = hi.y; bf_[s][6] = hi.z; bf_[s][7] = hi.w;
    }
    LGKM0();
    BAR();
    if (t + 2 < NT) stage(t + 2, buf);
    #pragma unroll
    for (int ms = 0; ms < 2; ++ms)
      #pragma unroll
      for (int ns = 0; ns < 2; ++ns)
        acc[ms][ns] = __builtin_amdgcn_mfma_scale_f32_32x32x64_f8f6f4(
            af[ms], bf_[ns], acc[ms][ns], 0, 0, 0, SCL1, 0, SCL1);
  }

  // ---- epilogue. 32x32 C/D: col = l31, row = (r&3) + 8*(r>>2) + 4*h ----
  float bv[2];
  #pragma unroll
  for (int ns = 0; ns < 2; ++ns) {
    int col = tn * 128 + wc * 64 + ns * 32 + l31;
    bv[ns] = (!NCHK || col < N) ? bias[col] : 0.f;
  }

  if (OMODE == 0) {
    // direct f32 stores: each (ms,r,ns) instr = rows {R, R+4} x 128B contiguous
    #pragma unroll
    for (int ms = 0; ms < 2; ++ms)
      #pragma unroll
      for (int r = 0; r < 16; ++r) {
        int row = tm * 128 + wr * 64 + ms * 32 + (r & 3) + ((r >> 2) << 3) + (h << 2);
        #pragma unroll
        for (int ns = 0; ns < 2; ++ns) {
          int col = tn * 128 + wc * 64 + ns * 32 + l31;
          if (NCHK && col >= N) continue;
          float v = acc[ms][ns][r] + bv[ns];
          if (ACT == 1) v = fmaxf(v, 0.f);
          if (ACT == 2) v = 1.f / (1.f + __expf(-v));
          Cf[(size_t)row * ldc + col] = v;
        }
      }
  } else {
    // f32 -> LDS (swizzled dwords) -> fp8 pack -> tiled store, 2 passes
    float* lf = (float*)lds;                 // [64][128] f32 = 32 KB
    #pragma unroll
    for (int p = 0; p < 2; ++p) {
      __syncthreads();
      if (wr == p) {
        #pragma unroll
        for (int ms = 0; ms < 2; ++ms)
          #pragma unroll
          for (int r = 0; r < 16; ++r) {
            int lrow = ms * 32 + (r & 3) + ((r >> 2) << 3) + (h << 2);  // 0..63
            #pragma unroll
            for (int ns = 0; ns < 2; ++ns) {
              int col = wc * 64 + ns * 32 + l31;                        // 0..127
              float v = acc[ms][ns][r] + bv[ns];
              if (ACT == 1) v = fmaxf(v, 0.f);
              lf[lrow * 128 + (((col >> 2) ^ (lrow & 31)) << 2) + (col & 3)] = v;
            }
          }
      }
      __syncthreads();
      #pragma unroll
      for (int it = 0; it < 2; ++it) {
        int idx = it * 256 + tid;            // 512 chunks of 16 cols
        int lrow = idx >> 3, cc = idx & 7;
        f32x4 q[4];
        #pragma unroll
        for (int s = 0; s < 4; ++s)
          q[s] = *(const f32x4*)&lf[lrow * 128 + (((cc * 4 + s) ^ (lrow & 31)) << 2)];
        int R = tm * 128 + p * 64 + lrow;
        int C = tn * 128 + cc * 16;
        int4 o;
        o.x = pack4fp8(q[0][0], q[0][1], q[0][2], q[0][3]);
        o.y = pack4fp8(q[1][0], q[1][1], q[1][2], q[1][3]);
        o.z = pack4fp8(q[2][0], q[2][1], q[2][2], q[2][3]);
        o.w = pack4fp8(q[3][0], q[3][1], q[3][2], q[3][3]);
        size_t off = ((size_t)(R >> 8) * (ldc >> 6) + (C >> 6)) * 16384
                   + ((R & 255) << 6) + ((((C >> 4) & 3) ^ FSWZ(R)) << 4);
        *(int4*)&Cb[off] = o;
      }
    }
  }
}

// =========================================================================
// Fused z = hB @ We3^T + be3 ; scores = z @ emb^T ; argmin ; q gather ; loss
// =========================================================================
__global__ __launch_bounds__(256, 1)
void z_vq(const u8* __restrict__ Atiled,       // hB fp8 tiled, K=1024
          const u8* __restrict__ Wrm,          // We3 fp8 row-major [64][1024]
          const float* __restrict__ be3,
          const u16* __restrict__ ebf,         // emb bf16 rm64-swz [512][64]
          const float* __restrict__ cvec,
          u8* __restrict__ qb8, float* __restrict__ lossacc) {
  __shared__ u8 lsA[2][128 * 64];
  __shared__ u8 lsW[2][64 * 64];
  __shared__ u16 embl[512 * 64];
  __shared__ float zls[128 * 68];
  __shared__ int bidxl[128];

  const int t = threadIdx.x;
  const int lane = t & 63;
  const int w = t >> 6;
  const int lr = lane & 15, hi = lane >> 4;
  const int tm = blockIdx.x;

  #pragma unroll
  for (int i = 0; i < 16; ++i) {
    const u16* g = ebf + (size_t)((i * 256 + t) << 3);
    u16* l = embl + (size_t)((i * 256 + w * 64) << 3);
    GLDS(g, l);
  }

  const size_t abase0 = ((size_t)(tm >> 1) * 16) * 16384 + (size_t)(tm & 1) * 8192;
  auto stageA = [&](int kt, int buf) {
    #pragma unroll
    for (int i = 0; i < 2; ++i) {
      const u8* g = Atiled + abase0 + (size_t)kt * 16384 + ((i * 256 + t) << 4);
      u8* l = lsA[buf] + ((i * 256 + w * 64) << 4);
      GLDS(g, l);
    }
  };
  auto stageW = [&](int kt, int buf) {
    int row = w * 16 + (lane >> 2), p = lane & 3;
    const u8* g = Wrm + (size_t)row * 1024 + kt * 64 + ((p ^ FSWZ(row)) << 4);
    u8* l = lsW[buf] + ((w * 64) << 4);
    GLDS(g, l);
  };

  f32x4 acc[2][4] = {};
  stageA(0, 0); stageW(0, 0);
  stageA(1, 1); stageW(1, 1);
  for (int kt = 0; kt < 16; ++kt) {
    const int bf = kt & 1;
    if (kt < 15) { VM3(); } else { VM0(); }
    BAR();
    #pragma unroll
    for (int kk = 0; kk < 64; kk += 32) {
      long af[2], bfr[4];
      #pragma unroll
      for (int m = 0; m < 2; ++m) {
        int row = w * 32 + m * 16 + lr;
        int ch = ((kk >> 4) + (hi >> 1)) ^ FSWZ(row);
        af[m] = *(const long*)&lsA[bf][row * 64 + ch * 16 + ((hi & 1) << 3)];
      }
      #pragma unroll
      for (int n = 0; n < 4; ++n) {
        int row = n * 16 + lr;
        int ch = ((kk >> 4) + (hi >> 1)) ^ FSWZ(row);
        bfr[n] = *(const long*)&lsW[bf][row * 64 + ch * 16 + ((hi & 1) << 3)];
      }
      #pragma unroll
      for (int m = 0; m < 2; ++m)
        #pragma unroll
        for (int n = 0; n < 4; ++n)
          acc[m][n] = __builtin_amdgcn_mfma_f32_16x16x32_fp8_fp8(af[m], bfr[n], acc[m][n], 0, 0, 0);
    }
    LGKM0();
    BAR();
    if (kt + 2 < 16) { stageA(kt + 2, bf); stageW(kt + 2, bf); }
  }

  #pragma unroll
  for (int m = 0; m < 2; ++m)
    #pragma unroll
    for (int j = 0; j < 4; ++j) {
      int row = w * 32 + m * 16 + hi * 4 + j;
      #pragma unroll
      for (int n = 0; n < 4; ++n) {
        int col = n * 16 + lr;
        zls[row * 68 + col] = acc[m][n][j] + be3[col];
      }
    }
  __syncthreads();

  bf16x8 azf[2][2];
  #pragma unroll
  for (int rt = 0; rt < 2; ++rt)
    #pragma unroll
    for (int kf = 0; kf < 2; ++kf) {
      int row = w * 32 + rt * 16 + lr;
      union { bf16x8 v; u16 u[8]; } pk;
      #pragma unroll
      for (int e = 0; e < 8; ++e)
        pk.u[e] = f2bf(zls[row * 68 + kf * 32 + hi * 8 + e]);
      azf[rt][kf] = pk.v;
    }

  float bvv[2][4]; int bii[2][4];
  #pragma unroll
  for (int rt = 0; rt < 2; ++rt)
    #pragma unroll
    for (int j = 0; j < 4; ++j) { bvv[rt][j] = 3.4e38f; bii[rt][j] = 0; }

  for (int ct = 0; ct < 32; ++ct) {
    bf16x8 bqf[2];
    #pragma unroll
    for (int kf = 0; kf < 2; ++kf) {
      int row = ct * 16 + lr;
      int ch = (kf * 4 + hi) ^ (row & 7);
      bqf[kf] = *(const bf16x8*)&embl[row * 64 + ch * 8];
    }
    float cv = cvec[ct * 16 + lr];
    #pragma unroll
    for (int rt = 0; rt < 2; ++rt) {
      f32x4 sc = {};
      sc = __builtin_amdgcn_mfma_f32_16x16x32_bf16(azf[rt][0], bqf[0], sc, 0, 0, 0);
      sc = __builtin_amdgcn_mfma_f32_16x16x32_bf16(azf[rt][1], bqf[1], sc, 0, 0, 0);
      int code = ct * 16 + lr;
      #pragma unroll
      for (int j = 0; j < 4; ++j) {
        float d = cv - sc[j];
        if (d < bvv[rt][j]) { bvv[rt][j] = d; bii[rt][j] = code; }
      }
    }
  }
  #pragma unroll
  for (int off = 1; off < 16; off <<= 1) {
    #pragma unroll
    for (int rt = 0; rt < 2; ++rt)
      #pragma unroll
      for (int j = 0; j < 4; ++j) {
        float ov = __shfl_xor(bvv[rt][j], off);
        int   oi = __shfl_xor(bii[rt][j], off);
        if (ov < bvv[rt][j] || (ov == bvv[rt][j] && oi < bii[rt][j])) {
          bvv[rt][j] = ov; bii[rt][j] = oi;
        }
      }
  }
  if (lr == 0) {
    #pragma unroll
    for (int rt = 0; rt < 2; ++rt)
      #pragma unroll
      for (int j = 0; j < 4; ++j)
        bidxl[w * 32 + rt * 16 + hi * 4 + j] = bii[rt][j];
  }
  __syncthreads();

  const int gr0 = tm * 128;
  float ls = 0.f;
  #pragma unroll 4
  for (int r8 = 0; r8 < 32; ++r8) {
    int row = w * 32 + r8;
    int bi = bidxl[row];
    u16 qu = embl[bi * 64 + (((lane >> 3) ^ (bi & 7)) << 3) + (lane & 7)];
    float qf = bf2f(qu);
    float d = qf - zls[row * 68 + lane];
    ls += d * d;
    int R = gr0 + row;
    qb8[(size_t)R * 64 + ((((lane >> 4) & 3) ^ FSWZ(R)) << 4) + (lane & 15)] = f2fp8(qf);
  }
  #pragma unroll
  for (int off = 32; off > 0; off >>= 1) ls += __shfl_down(ls, off);
  if (lane == 0) atomicAdd(lossacc, ls);
}

__global__ void loss_final(const float* __restrict__ acc, float* __restrict__ o, float denom) {
  o[0] = acc[0] * 1.25f / denom;
}

// ---------- launch ----------
extern "C" void kernel_launch(void* const* d_in, const int* in_sizes, int n_in,
                              void* d_out, int out_size, void* d_ws, size_t ws_size,
                              hipStream_t stream) {
  const float* x   = (const float*)d_in[0];
  const float* emb = (const float*)d_in[1];
  const float* We1 = (const float*)d_in[2];
  const float* be1 = (const float*)d_in[3];
  const float* We2 = (const float*)d_in[4];
  const float* be2 = (const float*)d_in[5];
  const float* We3 = (const float*)d_in[6];
  const float* be3 = (const float*)d_in[7];
  const float* Wd1 = (const float*)d_in[8];
  const float* bd1 = (const float*)d_in[9];
  const float* Wd2 = (const float*)d_in[10];
  const float* bd2 = (const float*)d_in[11];
  const float* Wd3 = (const float*)d_in[12];
  const float* bd3 = (const float*)d_in[13];

  const int Bn = in_sizes[0] / NIN;              // 32768
  float* out = (float*)d_out;
  float* out_loss = out + (size_t)Bn * NIN;

  char* ws = (char*)d_ws;
  size_t off = 0;
  auto take = [&](size_t bytes) { char* p = ws + off; off += (bytes + 255) & ~(size_t)255; return p; };

  u8*    xpad8 = (u8*)take((size_t)Bn * NINP);     // fp8 tiled
  u8*    hA8   = (u8*)take((size_t)Bn * NH);       // fp8 tiled: h1 -> h3
  u8*    hB8   = (u8*)take((size_t)Bn * NH);       // fp8 tiled: h2 -> h4
  u8*    qb8   = (u8*)take((size_t)Bn * ND);       // fp8 tiled (Cp=64)
  u8*    we1p8 = (u8*)take((size_t)NH * NINP);     // fp8 tiled
  u8*    we2b8 = (u8*)take((size_t)NH * NH);       // fp8 tiled
  u8*    we3r8 = (u8*)take((size_t)64 * NH);       // fp8 row-major
  u8*    wd1b8 = (u8*)take((size_t)NH * ND);       // fp8 tiled (Cp=64)
  u8*    wd2b8 = (u8*)take((size_t)NH * NH);       // fp8 tiled
  u8*    wd3p8 = (u8*)take((size_t)NOUTP * NH);    // fp8 tiled, rows 784+ zero
  u16*   embb  = (u16*)take((size_t)NE * ND * 2);  // bf16 rm64-swz
  float* cvec  = (float*)take(NE * 4);
  float* lossa = (float*)take(4);

  hipMemsetAsync(lossa, 0, 4, stream);

  cast_tiled8<<<dim3(1, Bn),    256, 0, stream>>>(x,   xpad8, Bn,  NIN, NINP);
  cast_tiled8<<<dim3(1, NH),    256, 0, stream>>>(We1, we1p8, NH,  NIN, NINP);
  cast_tiled8<<<dim3(1, NH),    256, 0, stream>>>(We2, we2b8, NH,  NH,  NH);
  cast_rm8   <<<dim3(1, 64),    256, 0, stream>>>(We3, we3r8, 64,  NH);
  cast_tiled8<<<dim3(1, NH),    256, 0, stream>>>(Wd1, wd1b8, NH,  ND,  ND);
  cast_tiled8<<<dim3(1, NH),    256, 0, stream>>>(Wd2, wd2b8, NH,  NH,  NH);
  cast_tiled8<<<dim3(1, NOUTP), 256, 0, stream>>>(Wd3, wd3p8, NIN, NH,  NH);
  emb_prep<<<NE, 64, 0, stream>>>(emb, embb, cvec);

  const int mt = Bn / 128;                       // 256 row-tiles
  // encoder
  gemm128mx<1,1,false><<<mt * 8, 256, 0, stream>>>(xpad8, we1p8, be1, nullptr, hA8, NH, NINP, NH, 8);
  gemm128mx<1,1,false><<<mt * 8, 256, 0, stream>>>(hA8, we2b8, be2, nullptr, hB8, NH, NH, NH, 8);
  // fused z + VQ
  z_vq<<<Bn / 128, 256, 0, stream>>>(hB8, we3r8, be3, embb, cvec, qb8, lossa);
  // decoder
  gemm128mx<1,1,false><<<mt * 8, 256, 0, stream>>>(qb8, wd1b8, bd1, nullptr, hA8, NH, 64, NH, 8);
  gemm128mx<1,1,false><<<mt * 8, 256, 0, stream>>>(hA8, wd2b8, bd2, nullptr, hB8, NH, NH, NH, 8);
  gemm128mx<2,0,true ><<<mt * 7, 256, 0, stream>>>(hB8, wd3p8, bd3, out, nullptr, NIN, NH, NIN, 7);

  loss_final<<<1, 1, 0, stream>>>(lossa, out_loss, (float)Bn * ND);
}